// Round 1
// baseline (117.949 us; speedup 1.0000x reference)
//
#include <hip/hip_runtime.h>

#define DIM   512
#define RANK  64
#define TDIM  1024
#define BB    2
#define NROWS (BB * TDIM)   // 2048 flattened rows per tensor

__device__ __forceinline__ float fast_exp2(float x) { return __builtin_amdgcn_exp2f(x); }
__device__ __forceinline__ float fast_rcp(float x)  { return __builtin_amdgcn_rcpf(x); }

// ---------------------------------------------------------------------------
// Projection: P[row][r] += X[row][kc..kc+63] . W[r][kc..kc+63]
// grid = (NROWS/64, DIM/64, 2)  -> 512 blocks, K split over gridDim.y,
// accumulated with atomicAdd into zero-initialized workspace.
// Block: 256 threads, 64 rows x 64 r tile, 4x4 per thread (strided indices
// so LDS b128 reads are <=2-way bank aliased = free).
// ---------------------------------------------------------------------------
__global__ __launch_bounds__(256)
void proj_kernel(const float* __restrict__ tv, const float* __restrict__ sv,
                 const float* __restrict__ Wt, const float* __restrict__ Ws,
                 float* __restrict__ pt, float* __restrict__ ps)
{
    const int which = blockIdx.z;
    const float* X = which ? sv : tv;
    const float* W = which ? Ws : Wt;
    float* P       = which ? ps : pt;

    const int row0 = blockIdx.x * 64;
    const int kc   = blockIdx.y * 64;
    const int tid  = threadIdx.x;
    const int tx   = tid & 15;
    const int ty   = tid >> 4;

    __shared__ float xs[64][68];
    __shared__ float wsm[64][68];

    // stage 64x64 chunks of X and W (coalesced float4, 4 passes each)
#pragma unroll
    for (int p = 0; p < 4; p++) {
        const int r = (tid >> 4) + p * 16;
        const int c = (tid & 15) * 4;
        *(float4*)&xs[r][c]  = *(const float4*)&X[(size_t)(row0 + r) * DIM + kc + c];
        *(float4*)&wsm[r][c] = *(const float4*)&W[(size_t)r * DIM + kc + c];
    }
    __syncthreads();

    float acc[4][4];
#pragma unroll
    for (int i = 0; i < 4; i++)
#pragma unroll
        for (int j = 0; j < 4; j++) acc[i][j] = 0.f;

#pragma unroll 2
    for (int k4 = 0; k4 < 64; k4 += 4) {
        float4 a[4], b[4];
#pragma unroll
        for (int i = 0; i < 4; i++) a[i] = *(const float4*)&xs[ty + 16 * i][k4];
#pragma unroll
        for (int j = 0; j < 4; j++) b[j] = *(const float4*)&wsm[tx + 16 * j][k4];
#pragma unroll
        for (int i = 0; i < 4; i++)
#pragma unroll
            for (int j = 0; j < 4; j++) {
                acc[i][j] = fmaf(a[i].x, b[j].x, acc[i][j]);
                acc[i][j] = fmaf(a[i].y, b[j].y, acc[i][j]);
                acc[i][j] = fmaf(a[i].z, b[j].z, acc[i][j]);
                acc[i][j] = fmaf(a[i].w, b[j].w, acc[i][j]);
            }
    }

#pragma unroll
    for (int i = 0; i < 4; i++)
#pragma unroll
        for (int j = 0; j < 4; j++)
            atomicAdd(&P[(size_t)(row0 + ty + 16 * i) * RANK + tx + 16 * j], acc[i][j]);
}

// ---------------------------------------------------------------------------
// Pairwise: out[b][t][s] = sum_r iw[r]*silu(pt[b,t,r]*ps[b,s,r])
//                          + tl[b,t] + sl[b,s] + bias
// grid = (S/64, T/64, B) = (16,16,2) -> 512 blocks, 2 blocks/CU.
// tl/sl recomputed per block from the staged LDS tiles (cheap).
// ---------------------------------------------------------------------------
__global__ __launch_bounds__(256)
void pair_kernel(const float* __restrict__ pt, const float* __restrict__ ps,
                 const float* __restrict__ wt_out, const float* __restrict__ ws_out,
                 const float* __restrict__ iw, const float* __restrict__ bias_p,
                 float* __restrict__ out)
{
    const int b  = blockIdx.z;
    const int t0 = blockIdx.y * 64;
    const int s0 = blockIdx.x * 64;
    const int tid = threadIdx.x;
    const int tx  = tid & 15;
    const int ty  = tid >> 4;

    __shared__ float pts[64][68];
    __shared__ float sts[64][68];
    __shared__ __align__(16) float wsh[64];
    __shared__ float tlsh[64];
    __shared__ float slsh[64];

    const float* ptb = pt + ((size_t)b * TDIM + t0) * RANK;
    const float* psb = ps + ((size_t)b * TDIM + s0) * RANK;

#pragma unroll
    for (int p = 0; p < 4; p++) {
        const int r = (tid >> 4) + p * 16;
        const int c = (tid & 15) * 4;
        *(float4*)&pts[r][c] = *(const float4*)&ptb[(size_t)r * RANK + c];
        *(float4*)&sts[r][c] = *(const float4*)&psb[(size_t)r * RANK + c];
    }
    if (tid < 64) wsh[tid] = iw[tid];
    __syncthreads();

    // per-block target/source linear terms (one wave each)
    if (tid < 64) {
        float v = 0.f;
#pragma unroll 8
        for (int r = 0; r < RANK; r++) v = fmaf(pts[tid][r], wt_out[r], v);
        tlsh[tid] = v;
    } else if (tid < 128) {
        const int s = tid - 64;
        float v = 0.f;
#pragma unroll 8
        for (int r = 0; r < RANK; r++) v = fmaf(sts[s][r], ws_out[r], v);
        slsh[s] = v;
    }
    __syncthreads();

    const float bias = bias_p[0];

    float acc[4][4];
#pragma unroll
    for (int i = 0; i < 4; i++)
#pragma unroll
        for (int j = 0; j < 4; j++) acc[i][j] = 0.f;

    const float NL2E = -1.44269504088896340736f;  // -log2(e)

#pragma unroll 2
    for (int r4 = 0; r4 < RANK; r4 += 4) {
        const float4 w4 = *(const float4*)&wsh[r4];
        const float wv[4] = {w4.x, w4.y, w4.z, w4.w};

        float a2[4][4], wa[4][4], bv[4][4];
#pragma unroll
        for (int i = 0; i < 4; i++) {
            const float4 a = *(const float4*)&pts[ty + 16 * i][r4];
            const float av[4] = {a.x, a.y, a.z, a.w};
#pragma unroll
            for (int k = 0; k < 4; k++) {
                a2[i][k] = av[k] * NL2E;    // feeds exp2
                wa[i][k] = av[k] * wv[k];   // feeds w*z
            }
        }
#pragma unroll
        for (int j = 0; j < 4; j++) {
            const float4 v = *(const float4*)&sts[tx + 16 * j][r4];
            bv[j][0] = v.x; bv[j][1] = v.y; bv[j][2] = v.z; bv[j][3] = v.w;
        }

#pragma unroll
        for (int i = 0; i < 4; i++)
#pragma unroll
            for (int j = 0; j < 4; j++)
#pragma unroll
                for (int k = 0; k < 4; k++) {
                    // z = a*b ; silu(z)*w = (w*z) * sigmoid(z)
                    const float t  = a2[i][k] * bv[j][k];      // -z*log2e
                    const float e  = fast_exp2(t);             // exp(-z)
                    const float rc = fast_rcp(1.0f + e);       // sigmoid(z)
                    acc[i][j] = fmaf(wa[i][k] * bv[j][k], rc, acc[i][j]);
                }
    }

    // epilogue: add linears + bias, coalesced scalar stores (lane tx contiguous)
#pragma unroll
    for (int i = 0; i < 4; i++) {
        const int t = t0 + ty + 16 * i;
        const float tl = tlsh[ty + 16 * i];
        float* orow = out + ((size_t)b * TDIM + t) * TDIM + s0;
#pragma unroll
        for (int j = 0; j < 4; j++) {
            orow[tx + 16 * j] = acc[i][j] + tl + slsh[tx + 16 * j] + bias;
        }
    }
}

// ---------------------------------------------------------------------------
extern "C" void kernel_launch(void* const* d_in, const int* in_sizes, int n_in,
                              void* d_out, int out_size, void* d_ws, size_t ws_size,
                              hipStream_t stream)
{
    const float* tv     = (const float*)d_in[0];  // [2,1024,512]
    const float* sv     = (const float*)d_in[1];  // [2,1024,512]
    const float* Wt     = (const float*)d_in[2];  // [64,512]
    const float* Ws     = (const float*)d_in[3];  // [64,512]
    const float* wt_out = (const float*)d_in[4];  // [64]
    const float* ws_out = (const float*)d_in[5];  // [64]
    const float* iw     = (const float*)d_in[6];  // [64]
    const float* bias   = (const float*)d_in[7];  // scalar
    float* out = (float*)d_out;                   // [2,1024,1024]

    float* pt = (float*)d_ws;                          // [2048][64]
    float* ps = pt + (size_t)NROWS * RANK;             // [2048][64]

    // zero projection accumulators (ws is poisoned before every launch)
    hipMemsetAsync(d_ws, 0, 2 * (size_t)NROWS * RANK * sizeof(float), stream);

    dim3 pgrid(NROWS / 64, DIM / 64, 2);
    proj_kernel<<<pgrid, 256, 0, stream>>>(tv, sv, Wt, Ws, pt, ps);

    dim3 ggrid(TDIM / 64, TDIM / 64, BB);
    pair_kernel<<<ggrid, 256, 0, stream>>>(pt, ps, wt_out, ws_out, iw, bias, out);
}